// Round 10
// baseline (129.382 us; speedup 1.0000x reference)
//
#include <hip/hip_runtime.h>
#include <math.h>
#include <stdint.h>

#define BATCH 8192
#define NS 4            // samples per block = waves per block
#define SLOT 2112       // uni slot stride in bytes (16-bank skew between samples)

typedef _Float16 f16;
typedef _Float16 f16x2 __attribute__((ext_vector_type(2)));
typedef _Float16 f16x8 __attribute__((ext_vector_type(8)));
typedef float f32x4 __attribute__((ext_vector_type(4)));
typedef uint32_t u32x4 __attribute__((ext_vector_type(4)));

__device__ __forceinline__ uint32_t pk2(float a, float b) {
    return __builtin_bit_cast(uint32_t, __builtin_amdgcn_cvt_pkrtz(a, b));
}
__device__ __forceinline__ uint32_t rfl_u(uint32_t v) {
    return (uint32_t)__builtin_amdgcn_readfirstlane((int)v);
}
__device__ __forceinline__ void wave_lds_fence() {
    asm volatile("s_waitcnt lgkmcnt(0)" ::: "memory");
}

// -----------------------------------------------------------------------------
// Pack:
//  w1p16 [64][800] f16, PIXEL-MAJOR k = p*16 + oc (k>=784 -> 0)
//  w2a   [16][96]  f16, k = tap*8 + ic (k>=72 -> 0): A-operand for conv2 MFMA.
// -----------------------------------------------------------------------------
__global__ __launch_bounds__(256) void pack_weights(
    const float* __restrict__ f1w, const float* __restrict__ c2w,
    uint32_t* __restrict__ w1p16, uint32_t* __restrict__ w2a)
{
    int idx = blockIdx.x * 256 + threadIdx.x;
    if (idx < 25600) {
        int o = idx / 400, pos = idx - o * 400;
        int k0 = 2 * pos, k1 = k0 + 1;
        float v0 = (k0 < 784) ? f1w[o * 784 + (k0 & 15) * 49 + (k0 >> 4)] : 0.f;
        float v1 = (k1 < 784) ? f1w[o * 784 + (k1 & 15) * 49 + (k1 >> 4)] : 0.f;
        w1p16[idx] = pk2(v0, v1);
    } else if (idx < 25600 + 768) {
        int i = idx - 25600;
        int oc = i / 48, pos = i - oc * 48;
        int k0 = 2 * pos, k1 = k0 + 1;
        float v0 = (k0 < 72) ? c2w[oc * 72 + (k0 & 7) * 9 + (k0 >> 3)] : 0.f;
        float v1 = (k1 < 72) ? c2w[oc * 72 + (k1 & 7) * 9 + (k1 >> 3)] : 0.f;
        w2a[i] = pk2(v0, v1);
    }
}

// -----------------------------------------------------------------------------
// Fused CNN. Block = 4 samples, 4 waves (256 thr). Wave s owns sample s through
// stages 0-2 (wave-private LDS, in-order DS pipe, no barriers). Then:
//   B1 -> FC1 MFMA (wave = 16 output units, K=800, B cols = 4 samples)
//   B2 -> FC2 shuffle-reduce -> logits
// This round: FC1 8-deep weight prefetch issued at KERNEL START (latency hides
// under conv1/conv2); s_setprio(1) around MFMA clusters (waves at different
// phases -> scheduler can favor MFMA-entering waves).
// -----------------------------------------------------------------------------
__global__ __launch_bounds__(256, 6) void fused_cnn(
    const float* __restrict__ x,        // [B,1,28,28]
    const float* __restrict__ c1w,      // [8,9]
    const float* __restrict__ c1b,      // [8]
    const f16* __restrict__ w2a,        // [16][96] packed conv2 A
    const float* __restrict__ c2b,      // [16]
    const f16* __restrict__ w1p16,      // [64][800] f16 packed, pixel-major
    const float* __restrict__ f1b,      // [64]
    const float* __restrict__ f2w,      // [4,64]
    const float* __restrict__ f2b,      // [4]
    float* __restrict__ logits)         // [B,4]
{
    const int tid  = threadIdx.x;
    const int lane = tid & 63;
    const int wid  = tid >> 6;          // wave = sample 0..3
    const int b0   = blockIdx.x * NS;

    __shared__ __align__(16) f16 h1[NS * 16 * 18 * 8];        // 18432 B
    __shared__ __align__(16) unsigned char uni[NS * SLOT];    // 8448 B
    float* shl = (float*)h1;            // [4][64] fp32 after B1 (h1 dead)

    const int col = lane & 15, grp = lane >> 4;

    // ---- early VMEM issues: image, conv2 A, FC1 weight prefetch ------------
    const float* xb = x + (size_t)(b0 + wid) * 784;
    const int i0 = lane, i1 = lane + 64, i2 = lane + 128;
    const int r0i = i0 / 7, c0i = i0 - 7 * r0i;
    const int r1i = i1 / 7, c1i = i1 - 7 * r1i;
    const int r2i = i2 / 7, c2i = i2 - 7 * r2i;
    float4 v0 = *(const float4*)(xb + r0i * 28 + c0i * 4);
    float4 v1 = *(const float4*)(xb + r1i * 28 + c1i * 4);
    float4 v2 = *(const float4*)(xb + r2i * 28 + c2i * 4);
    float4 v3 = make_float4(0.f, 0.f, 0.f, 0.f);
    if (lane < 4) v3 = *(const float4*)(xb + (lane + 192) / 7 * 28 + ((lane + 192) % 7) * 4);

    // conv2 A fragment: 3 aligned b128 loads (zeros for pad taps baked in)
    f16x8 af[3];
    int koff[3];
#pragma unroll
    for (int st = 0; st < 3; ++st) {
        af[st] = *(const f16x8*)(w2a + col * 96 + st * 32 + grp * 8);
        int tap = st * 4 + grp;
        if (tap < 9) {
            int ky = tap / 3, kx = tap - 3 * (tap / 3);
            koff[st] = (ky * 18 + kx) * 8;
        } else koff[st] = 0;
    }

    // FC1 weight prefetch, 8 deep — latency hides under stages 1-2
    const f16* wrow = w1p16 + (size_t)(wid * 16 + col) * 800 + grp * 8;
    f16x8 pa0 = *(const f16x8*)(wrow + 0 * 32);
    f16x8 pa1 = *(const f16x8*)(wrow + 1 * 32);
    f16x8 pa2 = *(const f16x8*)(wrow + 2 * 32);
    f16x8 pa3 = *(const f16x8*)(wrow + 3 * 32);
    f16x8 pa4 = *(const f16x8*)(wrow + 4 * 32);
    f16x8 pa5 = *(const f16x8*)(wrow + 5 * 32);
    f16x8 pa6 = *(const f16x8*)(wrow + 6 * 32);
    f16x8 pa7 = *(const f16x8*)(wrow + 7 * 32);

    // ---- per-wave zero of own simg + h1 regions ----------------------------
    {
        uint4 z = make_uint4(0, 0, 0, 0);
        uint4* zs = (uint4*)(uni + wid * SLOT);
        for (int i = lane; i < 128; i += 64) zs[i] = z;
        uint4* zh = (uint4*)(h1 + wid * 2304);
        for (int i = lane; i < 288; i += 64) zh[i] = z;
    }

    // conv1 packed weights -> SGPR (wave-uniform)
    f16x2 wpk[36], bpk[4];
#pragma unroll
    for (int t = 0; t < 9; ++t)
#pragma unroll
        for (int pr = 0; pr < 4; ++pr)
            wpk[t * 4 + pr] = __builtin_bit_cast(f16x2,
                rfl_u(pk2(c1w[(2 * pr) * 9 + t], c1w[(2 * pr + 1) * 9 + t])));
#pragma unroll
    for (int pr = 0; pr < 4; ++pr)
        bpk[pr] = __builtin_bit_cast(f16x2, rfl_u(pk2(c1b[2 * pr], c1b[2 * pr + 1])));
    wave_lds_fence();

    // ---- stage 0: image -> padded f16 LDS ----------------------------------
    {
        f16* simg = (f16*)(uni + wid * SLOT);
        int o0 = (r0i + 1) * 32 + 2 + 4 * c0i;
        *(uint32_t*)(simg + o0)     = pk2(v0.x, v0.y);
        *(uint32_t*)(simg + o0 + 2) = pk2(v0.z, v0.w);
        int o1 = (r1i + 1) * 32 + 2 + 4 * c1i;
        *(uint32_t*)(simg + o1)     = pk2(v1.x, v1.y);
        *(uint32_t*)(simg + o1 + 2) = pk2(v1.z, v1.w);
        int o2 = (r2i + 1) * 32 + 2 + 4 * c2i;
        *(uint32_t*)(simg + o2)     = pk2(v2.x, v2.y);
        *(uint32_t*)(simg + o2 + 2) = pk2(v2.z, v2.w);
        if (lane < 4) {
            int it = lane + 192;
            int o3 = (it / 7 + 1) * 32 + 2 + 4 * (it % 7);
            *(uint32_t*)(simg + o3)     = pk2(v3.x, v3.y);
            *(uint32_t*)(simg + o3 + 2) = pk2(v3.z, v3.w);
        }
    }
    wave_lds_fence();

    // ---- stage 1: conv1 + pool + relu (pk_fma, f16 accum) ------------------
    {
        const f16* simg = (const f16*)(uni + wid * SLOT);
        f16* h1s = h1 + wid * 2304;
#pragma unroll 1
        for (int pass = 0; pass < 4; ++pass) {
            int pix = pass * 64 + lane;       // pooled pixel over 196
            if (pix < 196) {
                int py = pix / 14, px = pix - 14 * py;
                f16x2 acc[2][2][4];
#pragma unroll
                for (int qy = 0; qy < 2; ++qy)
#pragma unroll
                for (int qx = 0; qx < 2; ++qx)
#pragma unroll
                for (int pr = 0; pr < 4; ++pr) acc[qy][qx][pr] = bpk[pr];

#pragma unroll
                for (int rr = 0; rr < 4; ++rr) {
                    const f16* rb = simg + (2 * py + rr) * 32 + 2 * px;
                    f16x2 A = *(const f16x2*)(rb);
                    f16x2 Bv = *(const f16x2*)(rb + 2);
                    f16x2 C = *(const f16x2*)(rb + 4);
                    f16 P[4] = { A[1], Bv[0], Bv[1], C[0] };
                    f16x2 sp[4];
#pragma unroll
                    for (int i = 0; i < 4; ++i) { sp[i][0] = P[i]; sp[i][1] = P[i]; }
#pragma unroll
                    for (int qy = 0; qy < 2; ++qy) {
                        int ky = rr - qy;
                        if (ky < 0 || ky > 2) continue;
#pragma unroll
                        for (int qx = 0; qx < 2; ++qx)
#pragma unroll
                        for (int kx = 0; kx < 3; ++kx) {
#pragma unroll
                            for (int pr = 0; pr < 4; ++pr)
                                acc[qy][qx][pr] = __builtin_elementwise_fma(
                                    sp[qx + kx], wpk[(ky * 3 + kx) * 4 + pr],
                                    acc[qy][qx][pr]);
                        }
                    }
                }
                f16x2 z; z[0] = (f16)0.f; z[1] = (f16)0.f;
                uint32_t ov[4];
#pragma unroll
                for (int pr = 0; pr < 4; ++pr) {
                    f16x2 m = __builtin_elementwise_max(
                        __builtin_elementwise_max(acc[0][0][pr], acc[0][1][pr]),
                        __builtin_elementwise_max(acc[1][0][pr], acc[1][1][pr]));
                    m = __builtin_elementwise_max(m, z);
                    ov[pr] = __builtin_bit_cast(uint32_t, m);
                }
                uint4 val = make_uint4(ov[0], ov[1], ov[2], ov[3]);
                *(uint4*)(h1s + ((py + 1) * 18 + (px + 1)) * 8) = val;
            }
        }
    }
    wave_lds_fence();

    // ---- stage 2: conv2 MFMA, N = 16 pooled pixels, pool-in-registers ------
    {
        const f16* h1b = h1 + wid * 2304;
        f16* sfeats = (f16*)(uni + wid * SLOT);
        f32x4 cb;
#pragma unroll
        for (int r = 0; r < 4; ++r) cb[r] = c2b[grp * 4 + r];

        __builtin_amdgcn_s_setprio(1);
#pragma unroll
        for (int T = 0; T < 4; ++T) {
            int p = 16 * T + col; p = p > 48 ? 48 : p;
            int py = (p * 9363) >> 16;                 // p / 7
            int px = p - 7 * py;
            const f16* base = h1b + (2 * py * 18 + 2 * px) * 8;
            f32x4 vmax = {-1e30f, -1e30f, -1e30f, -1e30f};
#pragma unroll
            for (int q = 0; q < 4; ++q) {
                const f16* bp = base + ((q >> 1) * 18 + (q & 1)) * 8;
                f32x4 c = {0.f, 0.f, 0.f, 0.f};
#pragma unroll
                for (int st = 0; st < 3; ++st) {
                    f16x8 bv = *(const f16x8*)(bp + koff[st]);
                    c = __builtin_amdgcn_mfma_f32_16x16x32_f16(af[st], bv, c, 0, 0, 0);
                }
                vmax = __builtin_elementwise_max(vmax, c);
            }
            if (16 * T + col <= 48) {
                uint2 val;
                val.x = pk2(fmaxf(vmax[0] + cb[0], 0.f), fmaxf(vmax[1] + cb[1], 0.f));
                val.y = pk2(fmaxf(vmax[2] + cb[2], 0.f), fmaxf(vmax[3] + cb[3], 0.f));
                *(uint2*)(sfeats + p * 16 + grp * 4) = val;
            }
        }
        __builtin_amdgcn_s_setprio(0);
        // zero FC1 K-pad region (indices 784..799)
        if (lane < 4) *(uint2*)(sfeats + 784 + lane * 4) = make_uint2(0u, 0u);
    }

    __syncthreads();                                   // B1

    // ---- stage 3: FC1 via MFMA (wave -> 16 units, B cols = 4 samples) ------
    {
        const int scol = col < NS ? col : 0;           // clamp B cols
        const f16* fb = (const f16*)(uni + scol * SLOT) + grp * 8;
        f32x4 c = {0.f, 0.f, 0.f, 0.f};
        __builtin_amdgcn_s_setprio(1);
        c = __builtin_amdgcn_mfma_f32_16x16x32_f16(pa0, *(const f16x8*)(fb + 0 * 32), c, 0, 0, 0);
        c = __builtin_amdgcn_mfma_f32_16x16x32_f16(pa1, *(const f16x8*)(fb + 1 * 32), c, 0, 0, 0);
        c = __builtin_amdgcn_mfma_f32_16x16x32_f16(pa2, *(const f16x8*)(fb + 2 * 32), c, 0, 0, 0);
        c = __builtin_amdgcn_mfma_f32_16x16x32_f16(pa3, *(const f16x8*)(fb + 3 * 32), c, 0, 0, 0);
        c = __builtin_amdgcn_mfma_f32_16x16x32_f16(pa4, *(const f16x8*)(fb + 4 * 32), c, 0, 0, 0);
        c = __builtin_amdgcn_mfma_f32_16x16x32_f16(pa5, *(const f16x8*)(fb + 5 * 32), c, 0, 0, 0);
        c = __builtin_amdgcn_mfma_f32_16x16x32_f16(pa6, *(const f16x8*)(fb + 6 * 32), c, 0, 0, 0);
        c = __builtin_amdgcn_mfma_f32_16x16x32_f16(pa7, *(const f16x8*)(fb + 7 * 32), c, 0, 0, 0);
#pragma unroll 5
        for (int st = 8; st < 25; ++st) {
            f16x8 a = *(const f16x8*)(wrow + st * 32);
            f16x8 b = *(const f16x8*)(fb + st * 32);
            c = __builtin_amdgcn_mfma_f32_16x16x32_f16(a, b, c, 0, 0, 0);
        }
        __builtin_amdgcn_s_setprio(0);
        if (col < NS) {
            const int u0 = wid * 16 + grp * 4;
            float4 h;
            h.x = fmaxf(c[0] + f1b[u0 + 0], 0.f);
            h.y = fmaxf(c[1] + f1b[u0 + 1], 0.f);
            h.z = fmaxf(c[2] + f1b[u0 + 2], 0.f);
            h.w = fmaxf(c[3] + f1b[u0 + 3], 0.f);
            *(float4*)(shl + col * 64 + u0) = h;
        }
    }
    __syncthreads();                                   // B2

    // ---- stage 4: FC2 (64->4), wave s = sample s ---------------------------
    {
        float hv = shl[wid * 64 + lane];
        float lg[4];
#pragma unroll
        for (int o = 0; o < 4; ++o) {
            float pv = hv * f2w[o * 64 + lane];
#pragma unroll
            for (int sft = 32; sft >= 1; sft >>= 1) pv += __shfl_xor(pv, sft);
            lg[o] = pv + f2b[o];
        }
        if (lane == 0) {
            float4 out4 = make_float4(lg[0], lg[1], lg[2], lg[3]);
            *(float4*)(logits + (size_t)(b0 + wid) * 4) = out4;
        }
    }
}

// -----------------------------------------------------------------------------
// Tail: each of 32 blocks redundantly reduces all logits -> BN stats; thread 0
// runs the (batch-constant) 4-qubit sim; block applies affine to its slice.
// -----------------------------------------------------------------------------
__global__ __launch_bounds__(256) void stats_apply(
    const float* __restrict__ logits, const float* __restrict__ var,
    const float* __restrict__ gamma, const float* __restrict__ beta,
    float* __restrict__ out)
{
    const int tid = threadIdx.x;
    const float4* l4 = (const float4*)logits;

    float t[8] = {0, 0, 0, 0, 0, 0, 0, 0};
#pragma unroll 4
    for (int i = 0; i < 32; ++i) {
        float4 v = l4[tid + 256 * i];
        t[0] += v.x; t[1] += v.y; t[2] += v.z; t[3] += v.w;
        t[4] += v.x * v.x; t[5] += v.y * v.y; t[6] += v.z * v.z; t[7] += v.w * v.w;
    }
#pragma unroll
    for (int sft = 32; sft >= 1; sft >>= 1)
#pragma unroll
        for (int j = 0; j < 8; ++j) t[j] += __shfl_xor(t[j], sft);

    __shared__ float part[4][8];
    __shared__ float prm[8];
    if ((tid & 63) == 0) {
#pragma unroll
        for (int j = 0; j < 8; ++j) part[tid >> 6][j] = t[j];
    }
    __syncthreads();

    if (tid == 0) {
        float sums[8];
#pragma unroll
        for (int j = 0; j < 8; ++j)
            sums[j] = part[0][j] + part[1][j] + part[2][j] + part[3][j];

        // 4-qubit statevector sim (ansatz + CNOT chain; feature-map RZ on
        // |0000> is a global phase -> batch-constant expectations)
        float pr[16], pi[16];
#pragma unroll
        for (int i = 0; i < 16; ++i) { pr[i] = 0.f; pi[i] = 0.f; }
        pr[0] = 1.f;
        for (int q = 0; q < 4; ++q) {
            float a  = var[3 * q], b_ = var[3 * q + 1], c = var[3 * q + 2];
            float ca = cosf(0.5f * a),  sa = sinf(0.5f * a);
            float cb = cosf(0.5f * b_), sb = sinf(0.5f * b_);
            float cc = cosf(0.5f * c),  sc = sinf(0.5f * c);
            float m00r = cb * ca, m00i =  sb * sa;
            float m01r = -sb * ca, m01i = -cb * sa;
            float m10r =  sb * ca, m10i = -cb * sa;
            float m11r =  cb * ca, m11i = -sb * sa;
            float u00r = cc * m00r + sc * m00i, u00i = cc * m00i - sc * m00r;
            float u01r = cc * m01r + sc * m01i, u01i = cc * m01i - sc * m01r;
            float u10r = cc * m10r - sc * m10i, u10i = cc * m10i + sc * m10r;
            float u11r = cc * m11r - sc * m11i, u11i = cc * m11i + sc * m11r;
            int stq = 1 << (3 - q);
            for (int i = 0; i < 16; ++i) {
                if (i & stq) continue;
                int j = i | stq;
                float xr = pr[i], xi = pi[i], yr = pr[j], yi = pi[j];
                pr[i] = u00r * xr - u00i * xi + u01r * yr - u01i * yi;
                pi[i] = u00r * xi + u00i * xr + u01r * yi + u01i * yr;
                pr[j] = u10r * xr - u10i * xi + u11r * yr - u11i * yi;
                pi[j] = u10r * xi + u10i * xr + u11r * yi + u11i * yr;
            }
        }
        for (int c = 0; c < 3; ++c) {
            int scm = 1 << (3 - c), stm = 1 << (2 - c);
            for (int i = 0; i < 16; ++i) {
                if ((i & scm) && !(i & stm)) {
                    int j = i | stm;
                    float tr = pr[i], ti = pi[i];
                    pr[i] = pr[j]; pi[i] = pi[j];
                    pr[j] = tr;    pi[j] = ti;
                }
            }
        }
        float p[16];
#pragma unroll
        for (int i = 0; i < 16; ++i) p[i] = pr[i] * pr[i] + pi[i] * pi[i];
        float e[4];
        for (int k = 0; k < 4; ++k) {
            float s = 0.f;
            for (int i = 0; i < 16; ++i)
                s += ((i >> (3 - k)) & 1) ? -p[i] : p[i];
            e[k] = s;
        }
        const float invB = 1.0f / (float)BATCH;
        for (int j = 0; j < 4; ++j) {
            float mu   = sums[j] * invB;
            float vr   = sums[4 + j] * invB - mu * mu;
            float istd = 1.0f / sqrtf(vr + 1e-5f);
            float scale = gamma[j] * istd;
            prm[j]     = scale;
            prm[4 + j] = beta[j] - mu * scale + e[3 - j];
        }
    }
    __syncthreads();

    const int smp = blockIdx.x * 256 + tid;
    float4 v = l4[smp];
    float4 r;
    r.x = v.x * prm[0] + prm[4];
    r.y = v.y * prm[1] + prm[5];
    r.z = v.z * prm[2] + prm[6];
    r.w = v.w * prm[3] + prm[7];
    ((float4*)out)[smp] = r;
}

extern "C" void kernel_launch(void* const* d_in, const int* in_sizes, int n_in,
                              void* d_out, int out_size, void* d_ws, size_t ws_size,
                              hipStream_t stream) {
    (void)in_sizes; (void)n_in; (void)out_size; (void)ws_size;
    const float* x   = (const float*)d_in[0];
    const float* c1w = (const float*)d_in[1];
    const float* c1b = (const float*)d_in[2];
    const float* c2w = (const float*)d_in[3];
    const float* c2b = (const float*)d_in[4];
    const float* f1w = (const float*)d_in[5];
    const float* f1b = (const float*)d_in[6];
    const float* f2w = (const float*)d_in[7];
    const float* f2b = (const float*)d_in[8];
    const float* gma = (const float*)d_in[9];
    const float* bta = (const float*)d_in[10];
    const float* var = (const float*)d_in[11];
    float* out = (float*)d_out;

    float*    logits = (float*)d_ws;                 // 131072 B
    uint32_t* w1p16  = (uint32_t*)(logits + 32768);  // 102400 B ([64][800] f16)
    uint32_t* w2a    = w1p16 + 25600;                // 3072 B   ([16][96] f16)

    pack_weights<<<103, 256, 0, stream>>>(f1w, c2w, w1p16, w2a);
    fused_cnn<<<BATCH / NS, 256, 0, stream>>>(x, c1w, c1b, (const f16*)w2a, c2b,
                                              (const f16*)w1p16, f1b, f2w, f2b,
                                              logits);
    stats_apply<<<32, 256, 0, stream>>>(logits, var, gma, bta, out);
}